// Round 3
// baseline (1934.163 us; speedup 1.0000x reference)
//
#include <hip/hip_runtime.h>

#define FPS_N 32768
#define FPS_T 1024
#define FPS_K 32      // points per thread
#define CHUNK 8       // pipeline chunk (double-buffered coord reload)
#define NQ 256
#define DD 256
#define NT 64         // n-tile for MLP kernel
#define B_BATCH 64

// ---------------------------------------------------------------------------
// Kernel 1: furthest point sampling, one block per batch.
// dist[32] in REGISTERS — __launch_bounds__(1024, 4) raises the VGPR cap to
// 128 (16-wave block = 4 waves/EU = real occupancy: 64 blocks / 256 CUs),
// preventing the 64-VGPR cap + scratch spill seen at R2.
// Coordinates re-streamed from L2 via double-buffered 8-point chunks.
// Arithmetic matches numpy bitwise: sub, mul, add (no FMA contraction), fminf.
// Tie-break: first occurrence (smallest index) like jnp.argmax.
// ---------------------------------------------------------------------------
__global__ __launch_bounds__(FPS_T, 4) void fps_kernel(const float* __restrict__ xyz,
                                                       float* __restrict__ qout) {
  const int b = blockIdx.x;
  const int t = threadIdx.x;
  const float* __restrict__ base = xyz + (size_t)b * (FPS_N * 3);
  float* qb = qout + (size_t)b * (NQ * 3);

  __shared__ float2 red[2][FPS_T / 64];   // (val, idx-bits), parity-buffered

  float dist[FPS_K];
#pragma unroll
  for (int k = 0; k < FPS_K; ++k) dist[k] = 1e10f;

  if (t == 0) { qb[0] = base[0]; qb[1] = base[1]; qb[2] = base[2]; }  // inds[0]==0
  float cx = base[0], cy = base[1], cz = base[2];

  for (int j = 1; j < NQ; ++j) {
    float best = -1.0f;
    int bi = 0;

    float lx[2][CHUNK], ly[2][CHUNK], lz[2][CHUNK];
    // prefetch chunk 0
#pragma unroll
    for (int i = 0; i < CHUNK; ++i) {
      const int p = i * FPS_T + t;
      lx[0][i] = base[3 * p + 0];
      ly[0][i] = base[3 * p + 1];
      lz[0][i] = base[3 * p + 2];
    }
#pragma unroll
    for (int c = 0; c < FPS_K / CHUNK; ++c) {
      const int cur = c & 1;
      if (c + 1 < FPS_K / CHUNK) {   // prefetch next chunk into other buffer
        const int nxt = cur ^ 1;
#pragma unroll
        for (int i = 0; i < CHUNK; ++i) {
          const int p = ((c + 1) * CHUNK + i) * FPS_T + t;
          lx[nxt][i] = base[3 * p + 0];
          ly[nxt][i] = base[3 * p + 1];
          lz[nxt][i] = base[3 * p + 2];
        }
      }
#pragma unroll
      for (int i = 0; i < CHUNK; ++i) {
        const int k = c * CHUNK + i;
        const float dx = __fsub_rn(lx[cur][i], cx);
        const float dy = __fsub_rn(ly[cur][i], cy);
        const float dz = __fsub_rn(lz[cur][i], cz);
        // numpy order: (dx^2 + dy^2) + dz^2, no fma
        const float d = __fadd_rn(__fadd_rn(__fmul_rn(dx, dx), __fmul_rn(dy, dy)),
                                  __fmul_rn(dz, dz));
        const float nd = fminf(dist[k], d);
        dist[k] = nd;
        if (nd > best) { best = nd; bi = k * FPS_T + t; }  // strict >: first occurrence
      }
    }

    // wave (64-lane) argmax reduce with first-index tie-break
#pragma unroll
    for (int off = 32; off; off >>= 1) {
      const float ov = __shfl_xor(best, off);
      const int oi = __shfl_xor(bi, off);
      if (ov > best || (ov == best && oi < bi)) { best = ov; bi = oi; }
    }
    if ((t & 63) == 0) {
      red[j & 1][t >> 6] = make_float2(best, __int_as_float(bi));
    }
    __syncthreads();
    // every thread reduces the 16 wave results redundantly (broadcast reads)
    float fv;
    int fi;
    {
      const float2 r0 = red[j & 1][0];
      fv = r0.x;
      fi = __float_as_int(r0.y);
#pragma unroll
      for (int w = 1; w < FPS_T / 64; ++w) {
        const float2 r = red[j & 1][w];
        const float ov = r.x;
        const int oi = __float_as_int(r.y);
        if (ov > fv || (ov == fv && oi < fi)) { fv = ov; fi = oi; }
      }
    }
    // fetch new centroid from global (same-address broadcast, L2-hot)
    const float* cp = base + 3 * (size_t)fi;
    cx = cp[0]; cy = cp[1]; cz = cp[2];
    if (t == 0) { qb[3 * j + 0] = cx; qb[3 * j + 1] = cy; qb[3 * j + 2] = cz; }
  }
}

// ---------------------------------------------------------------------------
// Kernel 2: fourier positional embedding + 2-layer MLP, fused. (unchanged)
// ---------------------------------------------------------------------------
__global__ __launch_bounds__(256) void embed_mlp_kernel(
    const float* __restrict__ qxyz, const float* __restrict__ pcmin,
    const float* __restrict__ pcmax, const float* __restrict__ G,
    const float* __restrict__ W1, const float* __restrict__ b1,
    const float* __restrict__ W2, const float* __restrict__ b2,
    float* __restrict__ out) {
  const int b = blockIdx.x >> 2;
  const int n0 = (blockIdx.x & 3) * NT;
  const int tid = threadIdx.x;
  const int ty = tid >> 4, tx = tid & 15;

  __shared__ __align__(16) float P[DD][NT + 4];   // pos
  __shared__ __align__(16) float H[DD][NT + 4];   // hidden
  __shared__ __align__(16) float Wl[64][NT + 4];  // W tile (transposed)
  __shared__ float snorm[NT][3];

  if (tid < NT) {
    const int n = n0 + tid;
    const float qx = qxyz[(size_t)b * (NQ * 3) + 3 * n + 0];
    const float qy = qxyz[(size_t)b * (NQ * 3) + 3 * n + 1];
    const float qz = qxyz[(size_t)b * (NQ * 3) + 3 * n + 2];
    snorm[tid][0] = (qx - pcmin[3 * b + 0]) / (pcmax[3 * b + 0] - pcmin[3 * b + 0]);
    snorm[tid][1] = (qy - pcmin[3 * b + 1]) / (pcmax[3 * b + 1] - pcmin[3 * b + 1]);
    snorm[tid][2] = (qz - pcmin[3 * b + 2]) / (pcmax[3 * b + 2] - pcmin[3 * b + 2]);
  }
  __syncthreads();

  {
    const int nn = tid & 63;
    const int fg = tid >> 6;   // 0..3
    const float nx = snorm[nn][0], ny = snorm[nn][1], nz = snorm[nn][2];
#pragma unroll 4
    for (int ff = 0; ff < 32; ++ff) {
      const int f = fg * 32 + ff;
      const float s = nx * G[f] + ny * G[128 + f] + nz * G[256 + f];
      const float proj = 6.28318530717958647692f * s;
      P[f][nn] = sinf(proj);
      P[f + 128][nn] = cosf(proj);
    }
  }

  for (int layer = 0; layer < 2; ++layer) {
    const float* W = layer ? W2 : W1;
    const float* bias = layer ? b2 : b1;
    const float (*src)[NT + 4] = layer ? H : P;

    for (int dt = 0; dt < 4; ++dt) {
      float acc[4][4] = {};
      for (int kt = 0; kt < 4; ++kt) {
        __syncthreads();
        {  // stage W tile transposed: Wl[c][d] = W[dt*64+d][kt*64+c]
          const int r = tid >> 2;
          const int cb = (tid & 3) * 16;
          const float* wrow = W + (size_t)(dt * 64 + r) * DD + kt * 64 + cb;
#pragma unroll
          for (int i = 0; i < 4; ++i) {
            const float4 v = *(const float4*)(wrow + 4 * i);
            Wl[cb + 4 * i + 0][r] = v.x;
            Wl[cb + 4 * i + 1][r] = v.y;
            Wl[cb + 4 * i + 2][r] = v.z;
            Wl[cb + 4 * i + 3][r] = v.w;
          }
        }
        __syncthreads();
#pragma unroll 8
        for (int cc = 0; cc < 64; ++cc) {
          const float4 a = *(const float4*)&Wl[cc][ty * 4];
          const float4 p4 = *(const float4*)&src[kt * 64 + cc][tx * 4];
          acc[0][0] = fmaf(a.x, p4.x, acc[0][0]);
          acc[0][1] = fmaf(a.x, p4.y, acc[0][1]);
          acc[0][2] = fmaf(a.x, p4.z, acc[0][2]);
          acc[0][3] = fmaf(a.x, p4.w, acc[0][3]);
          acc[1][0] = fmaf(a.y, p4.x, acc[1][0]);
          acc[1][1] = fmaf(a.y, p4.y, acc[1][1]);
          acc[1][2] = fmaf(a.y, p4.z, acc[1][2]);
          acc[1][3] = fmaf(a.y, p4.w, acc[1][3]);
          acc[2][0] = fmaf(a.z, p4.x, acc[2][0]);
          acc[2][1] = fmaf(a.z, p4.y, acc[2][1]);
          acc[2][2] = fmaf(a.z, p4.z, acc[2][2]);
          acc[2][3] = fmaf(a.z, p4.w, acc[2][3]);
          acc[3][0] = fmaf(a.w, p4.x, acc[3][0]);
          acc[3][1] = fmaf(a.w, p4.y, acc[3][1]);
          acc[3][2] = fmaf(a.w, p4.z, acc[3][2]);
          acc[3][3] = fmaf(a.w, p4.w, acc[3][3]);
        }
      }
      if (layer == 0) {
#pragma unroll
        for (int i = 0; i < 4; ++i) {
          const float bv = bias[dt * 64 + ty * 4 + i];
          float4 h;
          h.x = fmaxf(acc[i][0] + bv, 0.f);
          h.y = fmaxf(acc[i][1] + bv, 0.f);
          h.z = fmaxf(acc[i][2] + bv, 0.f);
          h.w = fmaxf(acc[i][3] + bv, 0.f);
          *(float4*)&H[dt * 64 + ty * 4 + i][tx * 4] = h;
        }
      } else {
        float* ob = out + (size_t)b * (DD * NQ);
#pragma unroll
        for (int i = 0; i < 4; ++i) {
          const float bv = bias[dt * 64 + ty * 4 + i];
          float4 h;
          h.x = fmaxf(acc[i][0] + bv, 0.f);
          h.y = fmaxf(acc[i][1] + bv, 0.f);
          h.z = fmaxf(acc[i][2] + bv, 0.f);
          h.w = fmaxf(acc[i][3] + bv, 0.f);
          *(float4*)(ob + (size_t)(dt * 64 + ty * 4 + i) * NQ + n0 + tx * 4) = h;
        }
      }
    }
  }
}

extern "C" void kernel_launch(void* const* d_in, const int* in_sizes, int n_in,
                              void* d_out, int out_size, void* d_ws, size_t ws_size,
                              hipStream_t stream) {
  (void)in_sizes; (void)n_in; (void)d_ws; (void)ws_size; (void)out_size;
  const float* xyz   = (const float*)d_in[0];
  const float* pcmin = (const float*)d_in[1];
  const float* pcmax = (const float*)d_in[2];
  const float* G     = (const float*)d_in[3];
  const float* W1    = (const float*)d_in[4];
  const float* b1    = (const float*)d_in[5];
  const float* W2    = (const float*)d_in[6];
  const float* b2    = (const float*)d_in[7];

  float* qxyz  = (float*)d_out;                       // [64][256][3]
  float* embed = qxyz + (size_t)B_BATCH * NQ * 3;     // [64][256][256]

  hipLaunchKernelGGL(fps_kernel, dim3(B_BATCH), dim3(FPS_T), 0, stream, xyz, qxyz);
  hipLaunchKernelGGL(embed_mlp_kernel, dim3(B_BATCH * 4), dim3(256), 0, stream,
                     qxyz, pcmin, pcmax, G, W1, b1, W2, b2, embed);
}

// Round 4
// 1111.551 us; speedup vs baseline: 1.7401x; 1.7401x over previous
//
#include <hip/hip_runtime.h>

#define FPS_N 32768
#define FPS_T 1024
#define FPS_K 32      // points per thread
#define NQ 256
#define DD 256
#define NT 64         // n-tile for MLP kernel
#define B_BATCH 64

// ---------------------------------------------------------------------------
// Kernel 1: furthest point sampling, one block per batch.
// Point assignment is per-thread-contiguous: thread t owns points
// [t*32, t*32+32). Each 4-point chunk is exactly 3 float4 loads at immediate
// offsets from a per-thread base (minimal address VALU), double-buffered so
// L2 latency hides under the previous chunk's compute. dist[32] in registers.
// amdgpu_waves_per_eu(4) raises the VGPR cap to 128 (16-wave block = 4
// waves/EU is the true occupancy: 64 blocks on 256 CUs) — the launch_bounds
// second arg was ignored by hipcc (R3: VGPR stuck at 64, scratch spill).
// Arithmetic matches numpy bitwise: sub, mul, add (no FMA), fminf.
// Tie-break: first occurrence (smallest global index) like jnp.argmax.
// ---------------------------------------------------------------------------
__global__ __attribute__((amdgpu_flat_work_group_size(FPS_T, FPS_T),
                          amdgpu_waves_per_eu(4)))
void fps_kernel(const float* __restrict__ xyz, float* __restrict__ qout) {
  const int b = blockIdx.x;
  const int t = threadIdx.x;
  const float* __restrict__ base = xyz + (size_t)b * (FPS_N * 3);
  const float4* __restrict__ base4 = (const float4*)base + (size_t)t * 24;
  float* qb = qout + (size_t)b * (NQ * 3);

  __shared__ float2 red[2][FPS_T / 64];   // (val, idx-bits), parity-buffered

  float dist[FPS_K];
#pragma unroll
  for (int k = 0; k < FPS_K; ++k) dist[k] = 1e10f;

  if (t == 0) { qb[0] = base[0]; qb[1] = base[1]; qb[2] = base[2]; }  // inds[0]==0
  float cx = base[0], cy = base[1], cz = base[2];

  for (int j = 1; j < NQ; ++j) {
    float best = -1.0f;
    int bik = 0;

    float4 bufA[3], bufB[3];
#pragma unroll
    for (int i = 0; i < 3; ++i) bufA[i] = base4[i];

#pragma unroll
    for (int c = 0; c < FPS_K / 4; ++c) {
      const float4* cur = (c & 1) ? bufB : bufA;
      float4* nxt = (c & 1) ? bufA : bufB;
      if (c < FPS_K / 4 - 1) {
#pragma unroll
        for (int i = 0; i < 3; ++i) nxt[i] = base4[3 * (c + 1) + i];
      }
      // unpack 12 floats -> 4 points (register renaming, no real ops)
      const float px[4] = {cur[0].x, cur[0].w, cur[1].z, cur[2].y};
      const float py[4] = {cur[0].y, cur[1].x, cur[1].w, cur[2].z};
      const float pz[4] = {cur[0].z, cur[1].y, cur[2].x, cur[2].w};
#pragma unroll
      for (int i = 0; i < 4; ++i) {
        const int k = c * 4 + i;
        const float dx = __fsub_rn(px[i], cx);
        const float dy = __fsub_rn(py[i], cy);
        const float dz = __fsub_rn(pz[i], cz);
        // numpy order: (dx^2 + dy^2) + dz^2, no fma
        const float d = __fadd_rn(__fadd_rn(__fmul_rn(dx, dx), __fmul_rn(dy, dy)),
                                  __fmul_rn(dz, dz));
        const float nd = fminf(dist[k], d);
        dist[k] = nd;
        if (nd > best) { best = nd; bik = k; }  // strict >: first occurrence
      }
    }
    int bi = (t << 5) | bik;   // global point index; lane order == index order

    // wave (64-lane) argmax reduce with first-index tie-break
#pragma unroll
    for (int off = 32; off; off >>= 1) {
      const float ov = __shfl_xor(best, off);
      const int oi = __shfl_xor(bi, off);
      if (ov > best || (ov == best && oi < bi)) { best = ov; bi = oi; }
    }
    if ((t & 63) == 0) {
      red[j & 1][t >> 6] = make_float2(best, __int_as_float(bi));
    }
    __syncthreads();
    // each lane reads ONE partial, then 16-lane xor-shuffle reduce (all lanes
    // converge to the same global argmax; replaces 16 LDS reads/thread)
    float fv;
    int fi;
    {
      const float2 r = red[j & 1][t & 15];
      fv = r.x;
      fi = __float_as_int(r.y);
#pragma unroll
      for (int off = 1; off < 16; off <<= 1) {
        const float ov = __shfl_xor(fv, off);
        const int oi = __shfl_xor(fi, off);
        if (ov > fv || (ov == fv && oi < fi)) { fv = ov; fi = oi; }
      }
    }
    // fetch new centroid from global (same-address broadcast, L2-hot)
    const float* cp = base + 3 * (size_t)fi;
    cx = cp[0]; cy = cp[1]; cz = cp[2];
    if (t == 0) { qb[3 * j + 0] = cx; qb[3 * j + 1] = cy; qb[3 * j + 2] = cz; }
  }
}

// ---------------------------------------------------------------------------
// Kernel 2: fourier positional embedding + 2-layer MLP, fused. (unchanged)
// ---------------------------------------------------------------------------
__global__ __launch_bounds__(256) void embed_mlp_kernel(
    const float* __restrict__ qxyz, const float* __restrict__ pcmin,
    const float* __restrict__ pcmax, const float* __restrict__ G,
    const float* __restrict__ W1, const float* __restrict__ b1,
    const float* __restrict__ W2, const float* __restrict__ b2,
    float* __restrict__ out) {
  const int b = blockIdx.x >> 2;
  const int n0 = (blockIdx.x & 3) * NT;
  const int tid = threadIdx.x;
  const int ty = tid >> 4, tx = tid & 15;

  __shared__ __align__(16) float P[DD][NT + 4];   // pos
  __shared__ __align__(16) float H[DD][NT + 4];   // hidden
  __shared__ __align__(16) float Wl[64][NT + 4];  // W tile (transposed)
  __shared__ float snorm[NT][3];

  if (tid < NT) {
    const int n = n0 + tid;
    const float qx = qxyz[(size_t)b * (NQ * 3) + 3 * n + 0];
    const float qy = qxyz[(size_t)b * (NQ * 3) + 3 * n + 1];
    const float qz = qxyz[(size_t)b * (NQ * 3) + 3 * n + 2];
    snorm[tid][0] = (qx - pcmin[3 * b + 0]) / (pcmax[3 * b + 0] - pcmin[3 * b + 0]);
    snorm[tid][1] = (qy - pcmin[3 * b + 1]) / (pcmax[3 * b + 1] - pcmin[3 * b + 1]);
    snorm[tid][2] = (qz - pcmin[3 * b + 2]) / (pcmax[3 * b + 2] - pcmin[3 * b + 2]);
  }
  __syncthreads();

  {
    const int nn = tid & 63;
    const int fg = tid >> 6;   // 0..3
    const float nx = snorm[nn][0], ny = snorm[nn][1], nz = snorm[nn][2];
#pragma unroll 4
    for (int ff = 0; ff < 32; ++ff) {
      const int f = fg * 32 + ff;
      const float s = nx * G[f] + ny * G[128 + f] + nz * G[256 + f];
      const float proj = 6.28318530717958647692f * s;
      P[f][nn] = sinf(proj);
      P[f + 128][nn] = cosf(proj);
    }
  }

  for (int layer = 0; layer < 2; ++layer) {
    const float* W = layer ? W2 : W1;
    const float* bias = layer ? b2 : b1;
    const float (*src)[NT + 4] = layer ? H : P;

    for (int dt = 0; dt < 4; ++dt) {
      float acc[4][4] = {};
      for (int kt = 0; kt < 4; ++kt) {
        __syncthreads();
        {  // stage W tile transposed: Wl[c][d] = W[dt*64+d][kt*64+c]
          const int r = tid >> 2;
          const int cb = (tid & 3) * 16;
          const float* wrow = W + (size_t)(dt * 64 + r) * DD + kt * 64 + cb;
#pragma unroll
          for (int i = 0; i < 4; ++i) {
            const float4 v = *(const float4*)(wrow + 4 * i);
            Wl[cb + 4 * i + 0][r] = v.x;
            Wl[cb + 4 * i + 1][r] = v.y;
            Wl[cb + 4 * i + 2][r] = v.z;
            Wl[cb + 4 * i + 3][r] = v.w;
          }
        }
        __syncthreads();
#pragma unroll 8
        for (int cc = 0; cc < 64; ++cc) {
          const float4 a = *(const float4*)&Wl[cc][ty * 4];
          const float4 p4 = *(const float4*)&src[kt * 64 + cc][tx * 4];
          acc[0][0] = fmaf(a.x, p4.x, acc[0][0]);
          acc[0][1] = fmaf(a.x, p4.y, acc[0][1]);
          acc[0][2] = fmaf(a.x, p4.z, acc[0][2]);
          acc[0][3] = fmaf(a.x, p4.w, acc[0][3]);
          acc[1][0] = fmaf(a.y, p4.x, acc[1][0]);
          acc[1][1] = fmaf(a.y, p4.y, acc[1][1]);
          acc[1][2] = fmaf(a.y, p4.z, acc[1][2]);
          acc[1][3] = fmaf(a.y, p4.w, acc[1][3]);
          acc[2][0] = fmaf(a.z, p4.x, acc[2][0]);
          acc[2][1] = fmaf(a.z, p4.y, acc[2][1]);
          acc[2][2] = fmaf(a.z, p4.z, acc[2][2]);
          acc[2][3] = fmaf(a.z, p4.w, acc[2][3]);
          acc[3][0] = fmaf(a.w, p4.x, acc[3][0]);
          acc[3][1] = fmaf(a.w, p4.y, acc[3][1]);
          acc[3][2] = fmaf(a.w, p4.z, acc[3][2]);
          acc[3][3] = fmaf(a.w, p4.w, acc[3][3]);
        }
      }
      if (layer == 0) {
#pragma unroll
        for (int i = 0; i < 4; ++i) {
          const float bv = bias[dt * 64 + ty * 4 + i];
          float4 h;
          h.x = fmaxf(acc[i][0] + bv, 0.f);
          h.y = fmaxf(acc[i][1] + bv, 0.f);
          h.z = fmaxf(acc[i][2] + bv, 0.f);
          h.w = fmaxf(acc[i][3] + bv, 0.f);
          *(float4*)&H[dt * 64 + ty * 4 + i][tx * 4] = h;
        }
      } else {
        float* ob = out + (size_t)b * (DD * NQ);
#pragma unroll
        for (int i = 0; i < 4; ++i) {
          const float bv = bias[dt * 64 + ty * 4 + i];
          float4 h;
          h.x = fmaxf(acc[i][0] + bv, 0.f);
          h.y = fmaxf(acc[i][1] + bv, 0.f);
          h.z = fmaxf(acc[i][2] + bv, 0.f);
          h.w = fmaxf(acc[i][3] + bv, 0.f);
          *(float4*)(ob + (size_t)(dt * 64 + ty * 4 + i) * NQ + n0 + tx * 4) = h;
        }
      }
    }
  }
}

extern "C" void kernel_launch(void* const* d_in, const int* in_sizes, int n_in,
                              void* d_out, int out_size, void* d_ws, size_t ws_size,
                              hipStream_t stream) {
  (void)in_sizes; (void)n_in; (void)d_ws; (void)ws_size; (void)out_size;
  const float* xyz   = (const float*)d_in[0];
  const float* pcmin = (const float*)d_in[1];
  const float* pcmax = (const float*)d_in[2];
  const float* G     = (const float*)d_in[3];
  const float* W1    = (const float*)d_in[4];
  const float* b1    = (const float*)d_in[5];
  const float* W2    = (const float*)d_in[6];
  const float* b2    = (const float*)d_in[7];

  float* qxyz  = (float*)d_out;                       // [64][256][3]
  float* embed = qxyz + (size_t)B_BATCH * NQ * 3;     // [64][256][256]

  hipLaunchKernelGGL(fps_kernel, dim3(B_BATCH), dim3(FPS_T), 0, stream, xyz, qxyz);
  hipLaunchKernelGGL(embed_mlp_kernel, dim3(B_BATCH * 4), dim3(256), 0, stream,
                     qxyz, pcmin, pcmax, G, W1, b1, W2, b2, embed);
}